// Round 4
// baseline (491824.463 us; speedup 1.0000x reference)
//
#include <hip/hip_runtime.h>
#include <hip/hip_bf16.h>

#define HID  1024
#define SEQT 8192
#define NBLK 256
#define TPB  256

// ws layout (floats):
// [0,1024)      int flagsA[1024]   (per-wave: h1(t) published when flagsA[w] == t+1)
// [1024,2048)   int flagsB[1024]   (per-wave: h2(t) published when flagsB[w] == t+1)
// [2048,4096)   float h1b[2][1024]
// [4096,6144)   float h2b[2][1024]
#define WS_FLOATS 6144

__device__ __forceinline__ float sig_(float x) { return 1.0f / (1.0f + expf(-x)); }

__device__ __forceinline__ float ld_agent(const float* p) {
    return __hip_atomic_load(p, __ATOMIC_RELAXED, __HIP_MEMORY_SCOPE_AGENT);
}
__device__ __forceinline__ void st_agent(float* p, float v) {
    __hip_atomic_store(p, v, __ATOMIC_RELAXED, __HIP_MEMORY_SCOPE_AGENT);
}
__device__ __forceinline__ void fence_acq_agent() {
    __builtin_amdgcn_fence(__ATOMIC_ACQUIRE, "agent");
}

// Wait until all 1024 per-wave flags reach >= tgt. 16 flags per lane.
__device__ __forceinline__ void wait_flags(const int* f, int tgt, int lane) {
    for (;;) {
        int mn = 0x7fffffff;
#pragma unroll
        for (int k = 0; k < 16; ++k) {
            int v = __hip_atomic_load(f + lane + 64 * k, __ATOMIC_RELAXED,
                                      __HIP_MEMORY_SCOPE_AGENT);
            mn = min(mn, v);
        }
        if (__all(mn >= tgt)) break;
    }
    fence_acq_agent();
}

extern "C" __global__ void __launch_bounds__(TPB, 1)
lstm_persist(const float* __restrict__ seq,
             const float* __restrict__ w_ih1, const float* __restrict__ w_hh1,
             const float* __restrict__ b_ih1, const float* __restrict__ b_hh1,
             const float* __restrict__ w_ih2, const float* __restrict__ w_hh2,
             const float* __restrict__ b_ih2, const float* __restrict__ b_hh2,
             const float* __restrict__ w_lin, const float* __restrict__ b_lin,
             float* __restrict__ out, float* ws)
{
    const int lane = threadIdx.x & 63;
    const int widx = threadIdx.x >> 6;
    const int w    = blockIdx.x * 4 + widx;   // owned hidden index 0..1023
    const int col0 = lane * 16;

    int*   flagsA = (int*)ws;                 // [1024]
    int*   flagsB = (int*)ws + 1024;          // [1024]
    float* h1b    = ws + 2048;                // [2][1024]
    float* h2b    = ws + 4096;                // [2][1024]

    // ---- load stationary weights into registers (coalesced float4) ----
    float w1[4][16], w2i[4][16], w2h[4][16];
#pragma unroll
    for (int g = 0; g < 4; ++g) {
        const float* r1 = w_hh1 + (size_t)(g * HID + w) * HID + col0;
        const float* r2 = w_ih2 + (size_t)(g * HID + w) * HID + col0;
        const float* r3 = w_hh2 + (size_t)(g * HID + w) * HID + col0;
#pragma unroll
        for (int m = 0; m < 16; m += 4) {
            float4 v1 = *(const float4*)(r1 + m);
            float4 v2 = *(const float4*)(r2 + m);
            float4 v3 = *(const float4*)(r3 + m);
            w1[g][m] = v1.x;  w1[g][m+1] = v1.y;  w1[g][m+2] = v1.z;  w1[g][m+3] = v1.w;
            w2i[g][m] = v2.x; w2i[g][m+1] = v2.y; w2i[g][m+2] = v2.z; w2i[g][m+3] = v2.w;
            w2h[g][m] = v3.x; w2h[g][m+1] = v3.y; w2h[g][m+2] = v3.z; w2h[g][m+3] = v3.w;
        }
    }
    float wx1[4], bb1[4], bb2[4];
#pragma unroll
    for (int g = 0; g < 4; ++g) {
        wx1[g] = w_ih1[g * HID + w];
        bb1[g] = b_ih1[g * HID + w] + b_hh1[g * HID + w];
        bb2[g] = b_ih2[g * HID + w] + b_hh2[g * HID + w];
    }
    const bool outwave = (w == 0);
    float wl[16];
#pragma unroll
    for (int m = 0; m < 16; ++m) wl[m] = 0.f;
    if (outwave) {
#pragma unroll
        for (int m = 0; m < 16; ++m) wl[m] = w_lin[col0 + m];
    }
    const float blin = b_lin[0];

    float c1 = 0.f, c2 = 0.f;

    for (int t = 0; t < SEQT; ++t) {
        const int cur = t & 1, prv = cur ^ 1;
        const float xt = seq[t];

        // ======== phase A : layer 1 (needs all of phase B of t-1) ========
        // flagsB >= t transitively implies flagsA >= t (hb-chain), so h1(t-1)
        // and h2(t-1) are both visible after this wait.
        wait_flags(flagsB, t, lane);

        // out(t-1) piggyback: h2(t-1) visible now
        if (outwave && t > 0) {
            float ov = 0.f;
#pragma unroll
            for (int m = 0; m < 16; ++m)
                ov = fmaf(wl[m], ld_agent(h2b + prv * HID + col0 + m), ov);
#pragma unroll
            for (int s = 32; s; s >>= 1) ov += __shfl_xor(ov, s);
            if (lane == 0) out[t - 1] = ov + blin;
        }

        float a0 = 0.f, a1 = 0.f, a2 = 0.f, a3 = 0.f;
        {
            float hv[16];
#pragma unroll
            for (int m = 0; m < 16; ++m)
                hv[m] = ld_agent(h1b + prv * HID + col0 + m);
#pragma unroll
            for (int m = 0; m < 16; ++m) {
                a0 = fmaf(w1[0][m], hv[m], a0);
                a1 = fmaf(w1[1][m], hv[m], a1);
                a2 = fmaf(w1[2][m], hv[m], a2);
                a3 = fmaf(w1[3][m], hv[m], a3);
            }
        }
#pragma unroll
        for (int s = 32; s; s >>= 1) {
            a0 += __shfl_xor(a0, s);
            a1 += __shfl_xor(a1, s);
            a2 += __shfl_xor(a2, s);
            a3 += __shfl_xor(a3, s);
        }
        if (lane == 0) {
            float gi = a0 + xt * wx1[0] + bb1[0];
            float gf = a1 + xt * wx1[1] + bb1[1];
            float gg = a2 + xt * wx1[2] + bb1[2];
            float go = a3 + xt * wx1[3] + bb1[3];
            float i_ = sig_(gi), f_ = sig_(gf), g_ = tanhf(gg), o_ = sig_(go);
            c1 = f_ * c1 + i_ * g_;
            float h1 = o_ * tanhf(c1);
            st_agent(h1b + cur * HID + w, h1);
            // release by the SAME lane that stored h1: single-thread ordering only
            __hip_atomic_store(flagsA + w, t + 1, __ATOMIC_RELEASE,
                               __HIP_MEMORY_SCOPE_AGENT);
        }

        // ======== phase B : layer 2 (needs all of phase A of t) ========
        // flagsA >= t+1 transitively implies flagsB >= t.
        wait_flags(flagsA, t + 1, lane);

        float g0 = 0.f, g1 = 0.f, g2 = 0.f, g3 = 0.f;
        {
            float hv1[16], hv2[16];
#pragma unroll
            for (int m = 0; m < 16; ++m) {
                hv1[m] = ld_agent(h1b + cur * HID + col0 + m);
                hv2[m] = ld_agent(h2b + prv * HID + col0 + m);
            }
#pragma unroll
            for (int m = 0; m < 16; ++m) {
                g0 = fmaf(w2i[0][m], hv1[m], g0);
                g1 = fmaf(w2i[1][m], hv1[m], g1);
                g2 = fmaf(w2i[2][m], hv1[m], g2);
                g3 = fmaf(w2i[3][m], hv1[m], g3);
            }
#pragma unroll
            for (int m = 0; m < 16; ++m) {
                g0 = fmaf(w2h[0][m], hv2[m], g0);
                g1 = fmaf(w2h[1][m], hv2[m], g1);
                g2 = fmaf(w2h[2][m], hv2[m], g2);
                g3 = fmaf(w2h[3][m], hv2[m], g3);
            }
        }
#pragma unroll
        for (int s = 32; s; s >>= 1) {
            g0 += __shfl_xor(g0, s);
            g1 += __shfl_xor(g1, s);
            g2 += __shfl_xor(g2, s);
            g3 += __shfl_xor(g3, s);
        }
        if (lane == 0) {
            float gi = g0 + bb2[0];
            float gf = g1 + bb2[1];
            float gg = g2 + bb2[2];
            float go = g3 + bb2[3];
            float i_ = sig_(gi), f_ = sig_(gf), g_ = tanhf(gg), o_ = sig_(go);
            c2 = f_ * c2 + i_ * g_;
            float h2 = o_ * tanhf(c2);
            st_agent(h2b + cur * HID + w, h2);
            __hip_atomic_store(flagsB + w, t + 1, __ATOMIC_RELEASE,
                               __HIP_MEMORY_SCOPE_AGENT);
        }
    }

    // final output, t = SEQT-1 (h2 buffer parity: (SEQT-1)&1 == 1)
    if (outwave) {
        wait_flags(flagsB, SEQT, lane);
        float ov = 0.f;
#pragma unroll
        for (int m = 0; m < 16; ++m)
            ov = fmaf(wl[m], ld_agent(h2b + 1 * HID + col0 + m), ov);
#pragma unroll
        for (int s = 32; s; s >>= 1) ov += __shfl_xor(ov, s);
        if (lane == 0) out[SEQT - 1] = ov + blin;
    }
}

extern "C" void kernel_launch(void* const* d_in, const int* in_sizes, int n_in,
                              void* d_out, int out_size, void* d_ws, size_t ws_size,
                              hipStream_t stream)
{
    (void)hipMemsetAsync(d_ws, 0, WS_FLOATS * sizeof(float), stream);

    const float* seq  = (const float*)d_in[0];
    const float* wih1 = (const float*)d_in[1];
    const float* whh1 = (const float*)d_in[2];
    const float* bih1 = (const float*)d_in[3];
    const float* bhh1 = (const float*)d_in[4];
    const float* wih2 = (const float*)d_in[5];
    const float* whh2 = (const float*)d_in[6];
    const float* bih2 = (const float*)d_in[7];
    const float* bhh2 = (const float*)d_in[8];
    const float* wlin = (const float*)d_in[9];
    const float* blin = (const float*)d_in[10];
    float* out = (float*)d_out;
    float* ws  = (float*)d_ws;

    // Regular launch (NOT cooperative): all sync is flag-based, and 256 blocks
    // at >=1 block/CU occupancy on a 256-CU chip are co-resident. Cooperative
    // launch failed silently and is not graph-capturable anyway.
    hipLaunchKernelGGL(lstm_persist, dim3(NBLK), dim3(TPB), 0, stream,
                       seq, wih1, whh1, bih1, bhh1,
                       wih2, whh2, bih2, bhh2, wlin, blin,
                       out, ws);
}

// Round 5
// 88954.889 us; speedup vs baseline: 5.5289x; 5.5289x over previous
//
#include <hip/hip_runtime.h>

#define HID   1024
#define SEQT  8192
#define NBLK  256
#define TPB   512   // 8 waves: widx 0-3 = layer1 rows, widx 4-7 = layer2 rows

// ws layout (floats):
// [0,256)       int flags[256]   (per-block phase counter)
// [256,1024)    pad
// [1024,3072)   float h1b[2][1024]   h1(t) lives in h1b[t&1]
// [3072,5120)   float h2b[2][1024]   h2(s) lives in h2b[s&1]
#define WS_FLOATS 5120

__device__ __forceinline__ float sig_(float x) { return 1.0f / (1.0f + expf(-x)); }

// Relaxed agent-scope atomics: compile to sc0|sc1 accesses that are serviced at
// the coherence point (MALL) -> cross-XCD visible WITHOUT wbl2/inv fences.
__device__ __forceinline__ float ldf(const float* p) {
    return __hip_atomic_load(p, __ATOMIC_RELAXED, __HIP_MEMORY_SCOPE_AGENT);
}
__device__ __forceinline__ void stf(float* p, float v) {
    __hip_atomic_store(p, v, __ATOMIC_RELAXED, __HIP_MEMORY_SCOPE_AGENT);
}
__device__ __forceinline__ int ldi(const int* p) {
    return __hip_atomic_load(p, __ATOMIC_RELAXED, __HIP_MEMORY_SCOPE_AGENT);
}
__device__ __forceinline__ void sti(int* p, int v) {
    __hip_atomic_store(p, v, __ATOMIC_RELAXED, __HIP_MEMORY_SCOPE_AGENT);
}

extern "C" __global__ void __launch_bounds__(TPB, 2)
lstm_pipe(const float* __restrict__ seq,
          const float* __restrict__ w_ih1, const float* __restrict__ w_hh1,
          const float* __restrict__ b_ih1, const float* __restrict__ b_hh1,
          const float* __restrict__ w_ih2, const float* __restrict__ w_hh2,
          const float* __restrict__ b_ih2, const float* __restrict__ b_hh2,
          const float* __restrict__ w_lin, const float* __restrict__ b_lin,
          float* __restrict__ out, float* ws)
{
    const int  lane = threadIdx.x & 63;
    const int  widx = threadIdx.x >> 6;        // 0..7
    const int  blk  = blockIdx.x;
    const bool isL1 = (widx < 4);
    const int  r    = blk * 4 + (widx & 3);    // owned hidden row 0..1023
    const int  col0 = lane * 16;

    int*   flags = (int*)ws;            // [256]
    float* h1b   = ws + 1024;           // [2][1024]
    float* h2b   = ws + 3072;           // [2][1024]

    // ---- stationary weights in registers ----
    // L1 wave: wa = w_hh1 rows (4 gates x 16 cols/lane)           = 64 regs
    // L2 wave: wa = w_ih2 rows, wb = w_hh2 rows                   = 128 regs
    float wa[4][16], wb[4][16], bb[4], wx[4];
#pragma unroll
    for (int g = 0; g < 4; ++g)
#pragma unroll
        for (int m = 0; m < 16; ++m) { wa[g][m] = 0.f; wb[g][m] = 0.f; }

    if (isL1) {
#pragma unroll
        for (int g = 0; g < 4; ++g) {
            const float* row = w_hh1 + (size_t)(g * HID + r) * HID + col0;
#pragma unroll
            for (int m = 0; m < 16; m += 4) {
                float4 v = *(const float4*)(row + m);
                wa[g][m] = v.x; wa[g][m+1] = v.y; wa[g][m+2] = v.z; wa[g][m+3] = v.w;
            }
            wx[g] = w_ih1[g * HID + r];
            bb[g] = b_ih1[g * HID + r] + b_hh1[g * HID + r];
        }
    } else {
#pragma unroll
        for (int g = 0; g < 4; ++g) {
            const float* ri = w_ih2 + (size_t)(g * HID + r) * HID + col0;
            const float* rh = w_hh2 + (size_t)(g * HID + r) * HID + col0;
#pragma unroll
            for (int m = 0; m < 16; m += 4) {
                float4 vi = *(const float4*)(ri + m);
                float4 vh = *(const float4*)(rh + m);
                wa[g][m] = vi.x; wa[g][m+1] = vi.y; wa[g][m+2] = vi.z; wa[g][m+3] = vi.w;
                wb[g][m] = vh.x; wb[g][m+1] = vh.y; wb[g][m+2] = vh.z; wb[g][m+3] = vh.w;
            }
            wx[g] = 0.f;
            bb[g] = b_ih2[g * HID + r] + b_hh2[g * HID + r];
        }
    }

    const bool outw = (blk == 0 && widx == 0);
    float wl[16]; float blin = 0.f;
#pragma unroll
    for (int m = 0; m < 16; ++m) wl[m] = 0.f;
    if (outw) {
#pragma unroll
        for (int m = 0; m < 16; ++m) wl[m] = w_lin[col0 + m];
        blin = b_lin[0];
    }

    float c = 0.f;   // c1 for L1 waves, c2 for L2 waves

    // Pipelined schedule, ONE device-wide phase per t:
    //   phase t: L1 computes h1(t)      [needs h1(t-1)]
    //            L2 computes h2(t-1)    [needs h1(t-1), h2(t-2)]
    //            OUT computes out(t-2)  [needs h2(t-2)]
    for (int t = 0; t <= SEQT + 1; ++t) {
        // ---- wait: all blocks finished phase t-1 (wave 0 polls, barrier gates rest)
        if (widx == 0 && t > 0) {
            int guard = 0;
            for (;;) {
                int f0 = ldi(flags + lane);
                int f1 = ldi(flags + lane + 64);
                int f2 = ldi(flags + lane + 128);
                int f3 = ldi(flags + lane + 192);
                int mn = min(min(f0, f1), min(f2, f3));
                if (__all(mn >= t)) break;
                if (++guard > (1 << 26)) break;   // failsafe: fail loud, not hung
            }
        }
        __syncthreads();

        const int cur = t & 1, prv = cur ^ 1;

        if (isL1) {
            if (t < SEQT) {
                float hv[16];
#pragma unroll
                for (int m = 0; m < 16; ++m)
                    hv[m] = ldf(h1b + prv * HID + col0 + m);
                float a0 = 0.f, a1 = 0.f, a2 = 0.f, a3 = 0.f;
#pragma unroll
                for (int m = 0; m < 16; ++m) {
                    a0 = fmaf(wa[0][m], hv[m], a0);
                    a1 = fmaf(wa[1][m], hv[m], a1);
                    a2 = fmaf(wa[2][m], hv[m], a2);
                    a3 = fmaf(wa[3][m], hv[m], a3);
                }
#pragma unroll
                for (int s = 32; s; s >>= 1) {
                    a0 += __shfl_xor(a0, s);
                    a1 += __shfl_xor(a1, s);
                    a2 += __shfl_xor(a2, s);
                    a3 += __shfl_xor(a3, s);
                }
                const float xt = seq[t];
                float i_ = sig_(a0 + xt * wx[0] + bb[0]);
                float f_ = sig_(a1 + xt * wx[1] + bb[1]);
                float g_ = tanhf(a2 + xt * wx[2] + bb[2]);
                float o_ = sig_(a3 + xt * wx[3] + bb[3]);
                c = f_ * c + i_ * g_;
                float h = o_ * tanhf(c);
                if (lane == 0) stf(h1b + cur * HID + r, h);
            }
            // out(t-2): h2(t-2) sits in h2b[(t-2)&1] == h2b[cur]
            if (outw && t >= 2) {
                float ov = 0.f;
#pragma unroll
                for (int m = 0; m < 16; ++m)
                    ov = fmaf(wl[m], ldf(h2b + cur * HID + col0 + m), ov);
#pragma unroll
                for (int s = 32; s; s >>= 1) ov += __shfl_xor(ov, s);
                if (lane == 0) out[t - 2] = ov + blin;
            }
        } else {
            if (t >= 1 && t <= SEQT) {
                float hv1[16], hv2[16];
#pragma unroll
                for (int m = 0; m < 16; ++m) {
                    hv1[m] = ldf(h1b + prv * HID + col0 + m);   // h1(t-1)
                    hv2[m] = ldf(h2b + cur * HID + col0 + m);   // h2(t-2)
                }
                float g0 = 0.f, g1 = 0.f, g2 = 0.f, g3 = 0.f;
#pragma unroll
                for (int m = 0; m < 16; ++m) {
                    g0 = fmaf(wa[0][m], hv1[m], g0);
                    g1 = fmaf(wa[1][m], hv1[m], g1);
                    g2 = fmaf(wa[2][m], hv1[m], g2);
                    g3 = fmaf(wa[3][m], hv1[m], g3);
                }
#pragma unroll
                for (int m = 0; m < 16; ++m) {
                    g0 = fmaf(wb[0][m], hv2[m], g0);
                    g1 = fmaf(wb[1][m], hv2[m], g1);
                    g2 = fmaf(wb[2][m], hv2[m], g2);
                    g3 = fmaf(wb[3][m], hv2[m], g3);
                }
#pragma unroll
                for (int s = 32; s; s >>= 1) {
                    g0 += __shfl_xor(g0, s);
                    g1 += __shfl_xor(g1, s);
                    g2 += __shfl_xor(g2, s);
                    g3 += __shfl_xor(g3, s);
                }
                float i_ = sig_(g0 + bb[0]);
                float f_ = sig_(g1 + bb[1]);
                float gg = tanhf(g2 + bb[2]);
                float o_ = sig_(g3 + bb[3]);
                c = f_ * c + i_ * gg;
                float h = o_ * tanhf(c);
                if (lane == 0) stf(h2b + prv * HID + r, h);   // h2(t-1) -> h2b[(t-1)&1]
            }
        }

        // ---- publish: barrier drains every wave's stores (vmcnt(0) before
        // s_barrier), so all h-values are at the MALL before the flag store.
        __syncthreads();
        if (threadIdx.x == 0) sti(flags + blk, t + 1);
        asm volatile("" ::: "memory");
    }
}

extern "C" void kernel_launch(void* const* d_in, const int* in_sizes, int n_in,
                              void* d_out, int out_size, void* d_ws, size_t ws_size,
                              hipStream_t stream)
{
    (void)hipMemsetAsync(d_ws, 0, WS_FLOATS * sizeof(float), stream);

    const float* seq  = (const float*)d_in[0];
    const float* wih1 = (const float*)d_in[1];
    const float* whh1 = (const float*)d_in[2];
    const float* bih1 = (const float*)d_in[3];
    const float* bhh1 = (const float*)d_in[4];
    const float* wih2 = (const float*)d_in[5];
    const float* whh2 = (const float*)d_in[6];
    const float* bih2 = (const float*)d_in[7];
    const float* bhh2 = (const float*)d_in[8];
    const float* wlin = (const float*)d_in[9];
    const float* blin = (const float*)d_in[10];
    float* out = (float*)d_out;
    float* ws  = (float*)d_ws;

    hipLaunchKernelGGL(lstm_pipe, dim3(NBLK), dim3(TPB), 0, stream,
                       seq, wih1, whh1, bih1, bhh1,
                       wih2, whh2, bih2, bhh2, wlin, blin,
                       out, ws);
}

// Round 6
// 40985.028 us; speedup vs baseline: 12.0001x; 2.1704x over previous
//
#include <hip/hip_runtime.h>

#define HID   1024
#define SEQT  8192
#define NBLK  256
#define TPB   512   // 8 waves: widx 0-3 = layer1 rows, widx 4-7 = layer2 rows

// ws layout (floats):
// [0,256)       int flags[256]   (per-block phase counter)
// [256,1024)    pad
// [1024,3072)   float h1b[2][1024]   h1(t) lives in h1b[t&1]
// [3072,5120)   float h2b[2][1024]   h2(s) lives in h2b[s&1]
#define WS_FLOATS 5120

typedef float v16f __attribute__((ext_vector_type(16)));

__device__ __forceinline__ float sig_(float x) { return 1.0f / (1.0f + expf(-x)); }

// Relaxed agent-scope atomics: serviced at the coherence point, cross-XCD
// visible without wbl2/inv fence traffic.
__device__ __forceinline__ float ldf(const float* p) {
    return __hip_atomic_load(p, __ATOMIC_RELAXED, __HIP_MEMORY_SCOPE_AGENT);
}
__device__ __forceinline__ void stf(float* p, float v) {
    __hip_atomic_store(p, v, __ATOMIC_RELAXED, __HIP_MEMORY_SCOPE_AGENT);
}
__device__ __forceinline__ int ldi(const int* p) {
    return __hip_atomic_load(p, __ATOMIC_RELAXED, __HIP_MEMORY_SCOPE_AGENT);
}
__device__ __forceinline__ void sti(int* p, int v) {
    __hip_atomic_store(p, v, __ATOMIC_RELAXED, __HIP_MEMORY_SCOPE_AGENT);
}

extern "C" __global__ void __launch_bounds__(TPB, 2)
lstm_pipe(const float* __restrict__ seq,
          const float* __restrict__ w_ih1, const float* __restrict__ w_hh1,
          const float* __restrict__ b_ih1, const float* __restrict__ b_hh1,
          const float* __restrict__ w_ih2, const float* __restrict__ w_hh2,
          const float* __restrict__ b_ih2, const float* __restrict__ b_hh2,
          const float* __restrict__ w_lin, const float* __restrict__ b_lin,
          float* __restrict__ out, float* ws)
{
    const int  lane = threadIdx.x & 63;
    const int  widx = threadIdx.x >> 6;        // 0..7
    const int  blk  = blockIdx.x;
    const bool isL1 = (widx < 4);
    const int  r    = blk * 4 + (widx & 3);    // owned hidden row 0..1023

    int*   flags = (int*)ws;            // [256]
    float* h1b   = ws + 1024;           // [2][1024]
    float* h2b   = ws + 3072;           // [2][1024]

    // Column ownership: lane holds columns {lane + 64k, k=0..15}.
    // Every h-load / weight-load is lane-consecutive => perfectly coalesced.
    // Dot products are full-wave reduced, so the permutation is harmless.

    // ---- stationary weights in REGISTERS (ext_vector vars, const subscripts)
    v16f A0, A1, A2, A3;   // L1: w_hh1 gate rows | L2: w_ih2 gate rows
    v16f B0, B1, B2, B3;   // L2: w_hh2 gate rows (unused by L1)
    float bb0, bb1, bb2, bb3, wx0, wx1, wx2, wx3;

    if (isL1) {
        const float* g0 = w_hh1 + (size_t)(0 * HID + r) * HID + lane;
        const float* g1 = w_hh1 + (size_t)(1 * HID + r) * HID + lane;
        const float* g2 = w_hh1 + (size_t)(2 * HID + r) * HID + lane;
        const float* g3 = w_hh1 + (size_t)(3 * HID + r) * HID + lane;
#pragma unroll
        for (int k = 0; k < 16; ++k) {
            A0[k] = g0[64 * k]; A1[k] = g1[64 * k];
            A2[k] = g2[64 * k]; A3[k] = g3[64 * k];
            B0[k] = 0.f; B1[k] = 0.f; B2[k] = 0.f; B3[k] = 0.f;
        }
        wx0 = w_ih1[0 * HID + r]; wx1 = w_ih1[1 * HID + r];
        wx2 = w_ih1[2 * HID + r]; wx3 = w_ih1[3 * HID + r];
        bb0 = b_ih1[0 * HID + r] + b_hh1[0 * HID + r];
        bb1 = b_ih1[1 * HID + r] + b_hh1[1 * HID + r];
        bb2 = b_ih1[2 * HID + r] + b_hh1[2 * HID + r];
        bb3 = b_ih1[3 * HID + r] + b_hh1[3 * HID + r];
    } else {
        const float* i0 = w_ih2 + (size_t)(0 * HID + r) * HID + lane;
        const float* i1 = w_ih2 + (size_t)(1 * HID + r) * HID + lane;
        const float* i2 = w_ih2 + (size_t)(2 * HID + r) * HID + lane;
        const float* i3 = w_ih2 + (size_t)(3 * HID + r) * HID + lane;
        const float* h0 = w_hh2 + (size_t)(0 * HID + r) * HID + lane;
        const float* h1 = w_hh2 + (size_t)(1 * HID + r) * HID + lane;
        const float* h2 = w_hh2 + (size_t)(2 * HID + r) * HID + lane;
        const float* h3 = w_hh2 + (size_t)(3 * HID + r) * HID + lane;
#pragma unroll
        for (int k = 0; k < 16; ++k) {
            A0[k] = i0[64 * k]; A1[k] = i1[64 * k];
            A2[k] = i2[64 * k]; A3[k] = i3[64 * k];
            B0[k] = h0[64 * k]; B1[k] = h1[64 * k];
            B2[k] = h2[64 * k]; B3[k] = h3[64 * k];
        }
        wx0 = wx1 = wx2 = wx3 = 0.f;
        bb0 = b_ih2[0 * HID + r] + b_hh2[0 * HID + r];
        bb1 = b_ih2[1 * HID + r] + b_hh2[1 * HID + r];
        bb2 = b_ih2[2 * HID + r] + b_hh2[2 * HID + r];
        bb3 = b_ih2[3 * HID + r] + b_hh2[3 * HID + r];
    }

    const bool outw = (blk == 0 && widx == 0);
    v16f WL;
    float blin = 0.f;
#pragma unroll
    for (int k = 0; k < 16; ++k) WL[k] = 0.f;
    if (outw) {
#pragma unroll
        for (int k = 0; k < 16; ++k) WL[k] = w_lin[lane + 64 * k];
        blin = b_lin[0];
    }

    float c = 0.f;   // c1 for L1 waves, c2 for L2 waves

    // Pipelined schedule, ONE device-wide phase per t:
    //   phase t: L1 computes h1(t)      [needs h1(t-1)]
    //            L2 computes h2(t-1)    [needs h1(t-1), h2(t-2)]
    //            OUT computes out(t-2)  [needs h2(t-2)]
    for (int t = 0; t <= SEQT + 1; ++t) {
        if (widx == 0 && t > 0) {
            int guard = 0;
            for (;;) {
                int f0 = ldi(flags + lane);
                int f1 = ldi(flags + lane + 64);
                int f2 = ldi(flags + lane + 128);
                int f3 = ldi(flags + lane + 192);
                int mn = min(min(f0, f1), min(f2, f3));
                if (__all(mn >= t)) break;
                if (++guard > (1 << 26)) break;   // failsafe: fail loud, not hung
            }
        }
        __syncthreads();

        const int cur = t & 1, prv = cur ^ 1;

        if (isL1) {
            if (t < SEQT) {
                const float* hp = h1b + prv * HID + lane;
                v16f hv;
#pragma unroll
                for (int k = 0; k < 16; ++k) hv[k] = ldf(hp + 64 * k);
                float a0 = 0.f, a1 = 0.f, a2 = 0.f, a3 = 0.f;
#pragma unroll
                for (int k = 0; k < 16; ++k) {
                    a0 = fmaf(A0[k], hv[k], a0);
                    a1 = fmaf(A1[k], hv[k], a1);
                    a2 = fmaf(A2[k], hv[k], a2);
                    a3 = fmaf(A3[k], hv[k], a3);
                }
#pragma unroll
                for (int s = 32; s; s >>= 1) {
                    a0 += __shfl_xor(a0, s);
                    a1 += __shfl_xor(a1, s);
                    a2 += __shfl_xor(a2, s);
                    a3 += __shfl_xor(a3, s);
                }
                const float xt = seq[t];
                float i_ = sig_(a0 + xt * wx0 + bb0);
                float f_ = sig_(a1 + xt * wx1 + bb1);
                float g_ = tanhf(a2 + xt * wx2 + bb2);
                float o_ = sig_(a3 + xt * wx3 + bb3);
                c = f_ * c + i_ * g_;
                float h = o_ * tanhf(c);
                if (lane == 0) stf(h1b + cur * HID + r, h);
            }
            // out(t-2): h2(t-2) sits in h2b[(t-2)&1] == h2b[cur]
            if (outw && t >= 2) {
                const float* hp = h2b + cur * HID + lane;
                float ov = 0.f;
#pragma unroll
                for (int k = 0; k < 16; ++k)
                    ov = fmaf(WL[k], ldf(hp + 64 * k), ov);
#pragma unroll
                for (int s = 32; s; s >>= 1) ov += __shfl_xor(ov, s);
                if (lane == 0) out[t - 2] = ov + blin;
            }
        } else {
            if (t >= 1 && t <= SEQT) {
                const float* hp1 = h1b + prv * HID + lane;   // h1(t-1)
                const float* hp2 = h2b + cur * HID + lane;   // h2(t-2)
                v16f hv1, hv2;
#pragma unroll
                for (int k = 0; k < 16; ++k) {
                    hv1[k] = ldf(hp1 + 64 * k);
                    hv2[k] = ldf(hp2 + 64 * k);
                }
                float g0 = 0.f, g1 = 0.f, g2 = 0.f, g3 = 0.f;
#pragma unroll
                for (int k = 0; k < 16; ++k) {
                    g0 = fmaf(A0[k], hv1[k], g0);
                    g1 = fmaf(A1[k], hv1[k], g1);
                    g2 = fmaf(A2[k], hv1[k], g2);
                    g3 = fmaf(A3[k], hv1[k], g3);
                }
#pragma unroll
                for (int k = 0; k < 16; ++k) {
                    g0 = fmaf(B0[k], hv2[k], g0);
                    g1 = fmaf(B1[k], hv2[k], g1);
                    g2 = fmaf(B2[k], hv2[k], g2);
                    g3 = fmaf(B3[k], hv2[k], g3);
                }
#pragma unroll
                for (int s = 32; s; s >>= 1) {
                    g0 += __shfl_xor(g0, s);
                    g1 += __shfl_xor(g1, s);
                    g2 += __shfl_xor(g2, s);
                    g3 += __shfl_xor(g3, s);
                }
                float i_ = sig_(g0 + bb0);
                float f_ = sig_(g1 + bb1);
                float gg = tanhf(g2 + bb2);
                float o_ = sig_(g3 + bb3);
                c = f_ * c + i_ * gg;
                float h = o_ * tanhf(c);
                if (lane == 0) stf(h2b + prv * HID + r, h);   // h2(t-1)
            }
        }

        // barrier drains every wave's stores (vmcnt(0) before s_barrier),
        // so all h-values are at the coherence point before the flag store.
        __syncthreads();
        if (threadIdx.x == 0) sti(flags + blk, t + 1);
    }
}

extern "C" void kernel_launch(void* const* d_in, const int* in_sizes, int n_in,
                              void* d_out, int out_size, void* d_ws, size_t ws_size,
                              hipStream_t stream)
{
    (void)hipMemsetAsync(d_ws, 0, WS_FLOATS * sizeof(float), stream);

    const float* seq  = (const float*)d_in[0];
    const float* wih1 = (const float*)d_in[1];
    const float* whh1 = (const float*)d_in[2];
    const float* bih1 = (const float*)d_in[3];
    const float* bhh1 = (const float*)d_in[4];
    const float* wih2 = (const float*)d_in[5];
    const float* whh2 = (const float*)d_in[6];
    const float* bih2 = (const float*)d_in[7];
    const float* bhh2 = (const float*)d_in[8];
    const float* wlin = (const float*)d_in[9];
    const float* blin = (const float*)d_in[10];
    float* out = (float*)d_out;
    float* ws  = (float*)d_ws;

    hipLaunchKernelGGL(lstm_pipe, dim3(NBLK), dim3(TPB), 0, stream,
                       seq, wih1, whh1, bih1, bhh1,
                       wih2, whh2, bih2, bhh2, wlin, blin,
                       out, ws);
}

// Round 8
// 25422.313 us; speedup vs baseline: 19.3462x; 1.6122x over previous
//
#include <hip/hip_runtime.h>

#define HID   1024
#define SEQT  8192
#define NBLK  256
#define TPB   512   // 8 waves: widx 0-3 = layer1 rows, widx 4-7 = layer2 rows

// ws (bytes): [0,16K) u64 h1t[2][1024] ; [16K,32K) u64 h2t[2][1024]
// packed slot: (tag<<32)|fp32_bits ; h(s) lives in slot s&1 with tag s+1; init 0
#define WS_BYTES 32768

typedef float v16f __attribute__((ext_vector_type(16)));
typedef unsigned long long u64;

__device__ __forceinline__ float sig_(float x) { return 1.0f / (1.0f + expf(-x)); }

__device__ __forceinline__ u64 ldp(const u64* p) {
    return __hip_atomic_load(p, __ATOMIC_RELAXED, __HIP_MEMORY_SCOPE_AGENT);
}
__device__ __forceinline__ void stp(u64* p, u64 v) {
    __hip_atomic_store(p, v, __ATOMIC_RELAXED, __HIP_MEMORY_SCOPE_AGENT);
}

extern "C" __global__ void __launch_bounds__(TPB, 2)
lstm_hyb(const float* __restrict__ seq,
         const float* __restrict__ w_ih1, const float* __restrict__ w_hh1,
         const float* __restrict__ b_ih1, const float* __restrict__ b_hh1,
         const float* __restrict__ w_ih2, const float* __restrict__ w_hh2,
         const float* __restrict__ b_ih2, const float* __restrict__ b_hh2,
         const float* __restrict__ w_lin, const float* __restrict__ b_lin,
         float* __restrict__ out, u64* ws)
{
    __shared__ float h1s[HID];    // h1(t-1) values, staged by wave 0
    __shared__ float h2s[HID];    // h2(t-2) values, staged by wave 4
    __shared__ float seqs[SEQT];  // whole input sequence (32 KB)

    const int  lane = threadIdx.x & 63;
    const int  widx = threadIdx.x >> 6;        // 0..7
    const bool isL1 = (widx < 4);
    const int  r    = blockIdx.x * 4 + (widx & 3);   // owned hidden row

    u64* h1t = ws;            // [2][1024]
    u64* h2t = ws + 2048;     // [2][1024]

    for (int i = threadIdx.x; i < SEQT; i += TPB) seqs[i] = seq[i];

    // ---- stationary weights, BRANCH-FREE load + unconditional use ----
    const float* bA  = isL1 ? w_hh1 : w_ih2;
    const float* bB  = isL1 ? w_hh1 : w_hh2;   // L1: B-dot zeroed via zmask
    const float* bbi = isL1 ? b_ih1 : b_ih2;
    const float* bbh = isL1 ? b_hh1 : b_hh2;
    const float  zmask = isL1 ? 0.f : 1.f;
    const float  xsel  = isL1 ? 1.f : 0.f;

    v16f A0, A1, A2, A3, B0, B1, B2, B3;
    {
        const size_t ro = (size_t)r * HID + lane;
        const float *a0 = bA + ro, *a1 = bA + (size_t)HID * HID + ro,
                    *a2 = bA + 2 * (size_t)HID * HID + ro, *a3 = bA + 3 * (size_t)HID * HID + ro;
        const float *b0 = bB + ro, *b1 = bB + (size_t)HID * HID + ro,
                    *b2 = bB + 2 * (size_t)HID * HID + ro, *b3 = bB + 3 * (size_t)HID * HID + ro;
#pragma unroll
        for (int k = 0; k < 16; ++k) {
            A0[k] = a0[64 * k]; A1[k] = a1[64 * k]; A2[k] = a2[64 * k]; A3[k] = a3[64 * k];
            B0[k] = b0[64 * k]; B1[k] = b1[64 * k]; B2[k] = b2[64 * k]; B3[k] = b3[64 * k];
        }
    }
    const float wx0 = w_ih1[0 * HID + r], wx1 = w_ih1[1 * HID + r],
                wx2 = w_ih1[2 * HID + r], wx3 = w_ih1[3 * HID + r];
    const float bb0 = bbi[0 * HID + r] + bbh[0 * HID + r];
    const float bb1 = bbi[1 * HID + r] + bbh[1 * HID + r];
    const float bb2 = bbi[2 * HID + r] + bbh[2 * HID + r];
    const float bb3 = bbi[3 * HID + r] + bbh[3 * HID + r];

    const bool carrier = (blockIdx.x == 0 && widx == 7);   // an L2 wave
    v16f WL; float blin = 0.f;
#pragma unroll
    for (int k = 0; k < 16; ++k) WL[k] = 0.f;
    if (carrier) {
#pragma unroll
        for (int k = 0; k < 16; ++k) WL[k] = w_lin[lane + 64 * k];
        blin = b_lin[0];
    }

    u64* pub = isL1 ? h1t : h2t;
    float c = 0.f;

    // Lock-step schedule, one device-wide phase per t (t = 0 .. SEQT+1):
    //   L1  computes h1(t)    [t < SEQT]   from h1(t-1)           (h1s)
    //   L2  computes h2(t-1)  [1<=t<=SEQT] from h1(t-1), h2(t-2)  (h1s,h2s)
    //   OUT computes out(t-2) [t >= 2]     from h2(t-2)           (h2s)
    // Overwrite safety: publishing h1(t) (slot t&1) clobbers h1(t-2); every
    // block reaching step t has seen h2(t-2) FULL, which requires every
    // block's step t-1 publishes, which follow their step t-1 polls -> no
    // block is still reading h1(t-2)/h2(t-3). Tags make torn reads impossible
    // (8B atomic) and the gating makes tag-too-new impossible mid-protocol.
    for (int t = 0; t <= SEQT + 1; ++t) {
        if (widx == 0 && t <= SEQT) {
            // poll h1(t-1): slot (t+1)&1, tag >= t (t=0: init tag 0 passes)
            const u64* p = h1t + ((t + 1) & 1) * HID + lane;
            int guard = 0;
            for (;;) {
                int mn = 0x7fffffff;
#pragma unroll
                for (int k = 0; k < 16; ++k) {
                    u64 q = ldp(p + 64 * k);
                    h1s[lane + 64 * k] = __uint_as_float((unsigned)q);
                    mn = min(mn, (int)(q >> 32));
                }
                if (__all(mn >= t)) break;
                if (++guard > (1 << 14)) break;   // bounded: fail loud, fast
            }
        }
        if (widx == 4) {
            // poll h2(t-2): slot t&1, tag >= t-1 (t<=1: init tag 0 passes)
            const u64* p = h2t + (t & 1) * HID + lane;
            const int thr = t - 1;
            int guard = 0;
            for (;;) {
                int mn = 0x7fffffff;
#pragma unroll
                for (int k = 0; k < 16; ++k) {
                    u64 q = ldp(p + 64 * k);
                    h2s[lane + 64 * k] = __uint_as_float((unsigned)q);
                    mn = min(mn, (int)(q >> 32));
                }
                if (__all(mn >= thr)) break;
                if (++guard > (1 << 14)) break;
            }
        }
        __syncthreads();

        const bool act = isL1 ? (t < SEQT) : (t >= 1 && t <= SEQT);
        if (act) {
            v16f v1, v2;
#pragma unroll
            for (int k = 0; k < 16; ++k) {
                v1[k] = h1s[lane + 64 * k];
                v2[k] = h2s[lane + 64 * k] * zmask;
            }
            float a0 = 0.f, a1 = 0.f, a2 = 0.f, a3 = 0.f;
#pragma unroll
            for (int k = 0; k < 16; ++k) {
                a0 = fmaf(A0[k], v1[k], a0);
                a1 = fmaf(A1[k], v1[k], a1);
                a2 = fmaf(A2[k], v1[k], a2);
                a3 = fmaf(A3[k], v1[k], a3);
            }
#pragma unroll
            for (int k = 0; k < 16; ++k) {
                a0 = fmaf(B0[k], v2[k], a0);
                a1 = fmaf(B1[k], v2[k], a1);
                a2 = fmaf(B2[k], v2[k], a2);
                a3 = fmaf(B3[k], v2[k], a3);
            }
#pragma unroll
            for (int s = 32; s; s >>= 1) {
                a0 += __shfl_xor(a0, s);
                a1 += __shfl_xor(a1, s);
                a2 += __shfl_xor(a2, s);
                a3 += __shfl_xor(a3, s);
            }
            const float xg = xsel * ((t < SEQT) ? seqs[t] : 0.f);
            float i_ = sig_(a0 + xg * wx0 + bb0);
            float f_ = sig_(a1 + xg * wx1 + bb1);
            float g_ = tanhf(a2 + xg * wx2 + bb2);
            float o_ = sig_(a3 + xg * wx3 + bb3);
            c = f_ * c + i_ * g_;
            float h = o_ * tanhf(c);
            if (lane == 0) {
                const int ps = isL1 ? t : (t - 1);   // produced timestep
                stp(pub + (ps & 1) * HID + r,
                    ((u64)(unsigned)(ps + 1) << 32) | (u64)__float_as_uint(h));
            }
        }

        // out(t-2) from staged h2s (carrier also did its row-gate work above)
        if (carrier && t >= 2) {
            float ov = 0.f;
#pragma unroll
            for (int k = 0; k < 16; ++k) ov = fmaf(WL[k], h2s[lane + 64 * k], ov);
#pragma unroll
            for (int s = 32; s; s >>= 1) ov += __shfl_xor(ov, s);
            if (lane == 0) out[t - 2] = ov + blin;
        }

        __syncthreads();   // protect LDS from next step's restaging
    }
}

extern "C" void kernel_launch(void* const* d_in, const int* in_sizes, int n_in,
                              void* d_out, int out_size, void* d_ws, size_t ws_size,
                              hipStream_t stream)
{
    (void)hipMemsetAsync(d_ws, 0, WS_BYTES, stream);

    const float* seq  = (const float*)d_in[0];
    const float* wih1 = (const float*)d_in[1];
    const float* whh1 = (const float*)d_in[2];
    const float* bih1 = (const float*)d_in[3];
    const float* bhh1 = (const float*)d_in[4];
    const float* wih2 = (const float*)d_in[5];
    const float* whh2 = (const float*)d_in[6];
    const float* bih2 = (const float*)d_in[7];
    const float* bhh2 = (const float*)d_in[8];
    const float* wlin = (const float*)d_in[9];
    const float* blin = (const float*)d_in[10];
    float* out = (float*)d_out;
    u64*   ws  = (u64*)d_ws;

    hipLaunchKernelGGL(lstm_hyb, dim3(NBLK), dim3(TPB), 0, stream,
                       seq, wih1, whh1, bih1, bhh1,
                       wih2, whh2, bih2, bhh2, wlin, blin,
                       out, ws);
}

// Round 9
// 24850.128 us; speedup vs baseline: 19.7916x; 1.0230x over previous
//
#include <hip/hip_runtime.h>

#define HID   1024
#define SEQT  8192
#define NBLK  256
#define TPB   512   // 8 waves: widx 0-3 = layer1 rows, widx 4-7 = layer2 rows

// ws (bytes): [0,16K) u64 h1t[2][1024] ; [16K,32K) u64 h2t[2][1024]
// packed slot: (tag<<32)|fp32_bits ; h(s) lives in slot s&1 with tag s+1; init 0
#define WS_BYTES 32768

typedef float v16f __attribute__((ext_vector_type(16)));
typedef unsigned long long u64;

__device__ __forceinline__ float sig_(float x) { return 1.0f / (1.0f + expf(-x)); }

__device__ __forceinline__ u64 ldp(const u64* p) {
    return __hip_atomic_load(p, __ATOMIC_RELAXED, __HIP_MEMORY_SCOPE_AGENT);
}
__device__ __forceinline__ void stp(u64* p, u64 v) {
    __hip_atomic_store(p, v, __ATOMIC_RELAXED, __HIP_MEMORY_SCOPE_AGENT);
}

// Pin an ext_vector into VGPRs: empty asm that "redefines" it, so the
// compiler cannot re-materialize the loads (forces true residency).
#define PIN(v) asm volatile("" : "+v"(v))

extern "C" __global__ void __launch_bounds__(TPB, 2)
lstm_hyb(const float* __restrict__ seq,
         const float* __restrict__ w_ih1, const float* __restrict__ w_hh1,
         const float* __restrict__ b_ih1, const float* __restrict__ b_hh1,
         const float* __restrict__ w_ih2, const float* __restrict__ w_hh2,
         const float* __restrict__ b_ih2, const float* __restrict__ b_hh2,
         const float* __restrict__ w_lin, const float* __restrict__ b_lin,
         float* __restrict__ out, u64* ws)
{
    __shared__ float h1s[HID];    // h1(t-1) values, staged by wave 0
    __shared__ float h2s[HID];    // h2(t-2) values, staged by wave 4
    __shared__ float seqs[SEQT];  // whole input sequence (32 KB)

    const int  lane = threadIdx.x & 63;
    const int  widx = threadIdx.x >> 6;        // 0..7
    const bool isL1 = (widx < 4);
    const int  r    = blockIdx.x * 4 + (widx & 3);   // owned hidden row

    u64* h1t = ws;            // [2][1024]
    u64* h2t = ws + 2048;     // [2][1024]

    for (int i = threadIdx.x; i < SEQT; i += TPB) seqs[i] = seq[i];

    // ---- stationary weights, BRANCH-FREE load + unconditional use ----
    const float* bA  = isL1 ? w_hh1 : w_ih2;
    const float* bB  = isL1 ? w_hh1 : w_hh2;   // L1: B-dot zeroed via zmask
    const float* bbi = isL1 ? b_ih1 : b_ih2;
    const float* bbh = isL1 ? b_hh1 : b_hh2;
    const float  zmask = isL1 ? 0.f : 1.f;
    const float  xsel  = isL1 ? 1.f : 0.f;

    v16f A0, A1, A2, A3, B0, B1, B2, B3;
    {
        const size_t ro = (size_t)r * HID + lane;
        const float *a0 = bA + ro, *a1 = bA + (size_t)HID * HID + ro,
                    *a2 = bA + 2 * (size_t)HID * HID + ro, *a3 = bA + 3 * (size_t)HID * HID + ro;
        const float *b0 = bB + ro, *b1 = bB + (size_t)HID * HID + ro,
                    *b2 = bB + 2 * (size_t)HID * HID + ro, *b3 = bB + 3 * (size_t)HID * HID + ro;
#pragma unroll
        for (int k = 0; k < 16; ++k) {
            A0[k] = a0[64 * k]; A1[k] = a1[64 * k]; A2[k] = a2[64 * k]; A3[k] = a3[64 * k];
            B0[k] = b0[64 * k]; B1[k] = b1[64 * k]; B2[k] = b2[64 * k]; B3[k] = b3[64 * k];
        }
    }
    // force materialization before the loop
    PIN(A0); PIN(A1); PIN(A2); PIN(A3);
    PIN(B0); PIN(B1); PIN(B2); PIN(B3);

    const float wx0 = w_ih1[0 * HID + r], wx1 = w_ih1[1 * HID + r],
                wx2 = w_ih1[2 * HID + r], wx3 = w_ih1[3 * HID + r];
    const float bb0 = bbi[0 * HID + r] + bbh[0 * HID + r];
    const float bb1 = bbi[1 * HID + r] + bbh[1 * HID + r];
    const float bb2 = bbi[2 * HID + r] + bbh[2 * HID + r];
    const float bb3 = bbi[3 * HID + r] + bbh[3 * HID + r];

    const bool carrier = (blockIdx.x == 0 && widx == 7);   // an L2 wave
    v16f WL; float blin = 0.f;
#pragma unroll
    for (int k = 0; k < 16; ++k) WL[k] = 0.f;
    if (carrier) {
#pragma unroll
        for (int k = 0; k < 16; ++k) WL[k] = w_lin[lane + 64 * k];
        blin = b_lin[0];
    }

    u64* pub = isL1 ? h1t : h2t;
    float c = 0.f;

    // Lock-step schedule, one device-wide phase per t (t = 0 .. SEQT+1):
    //   L1  computes h1(t)    [t < SEQT]   from h1(t-1)           (h1s)
    //   L2  computes h2(t-1)  [1<=t<=SEQT] from h1(t-1), h2(t-2)  (h1s,h2s)
    //   OUT computes out(t-2) [t >= 2]     from h2(t-2)           (h2s)
    // Overwrite safety: publishing h1(t) (slot t&1) clobbers h1(t-2); every
    // block reaching step t has seen h2(t-2) FULL, which requires every
    // block's step t-1 publishes, which follow their step t-1 polls -> no
    // block is still reading h1(t-2)/h2(t-3). Tags make torn reads impossible
    // (8B atomic) and the gating makes tag-too-new impossible mid-protocol.
    for (int t = 0; t <= SEQT + 1; ++t) {
        // keep every weight register loop-carried: compiler cannot sink the
        // loads into the loop (this is the fix for VGPR=116 weight streaming)
        PIN(A0); PIN(A1); PIN(A2); PIN(A3);
        PIN(B0); PIN(B1); PIN(B2); PIN(B3);

        if (widx == 0 && t <= SEQT) {
            // poll h1(t-1): slot (t+1)&1, tag >= t (t=0: init tag 0 passes)
            const u64* p = h1t + ((t + 1) & 1) * HID + lane;
            int guard = 0;
            for (;;) {
                int mn = 0x7fffffff;
#pragma unroll
                for (int k = 0; k < 16; ++k) {
                    u64 q = ldp(p + 64 * k);
                    h1s[lane + 64 * k] = __uint_as_float((unsigned)q);
                    mn = min(mn, (int)(q >> 32));
                }
                if (__all(mn >= t)) break;
                if (++guard > (1 << 14)) break;   // bounded: fail loud, fast
            }
        }
        if (widx == 4) {
            // poll h2(t-2): slot t&1, tag >= t-1 (t<=1: init tag 0 passes)
            const u64* p = h2t + (t & 1) * HID + lane;
            const int thr = t - 1;
            int guard = 0;
            for (;;) {
                int mn = 0x7fffffff;
#pragma unroll
                for (int k = 0; k < 16; ++k) {
                    u64 q = ldp(p + 64 * k);
                    h2s[lane + 64 * k] = __uint_as_float((unsigned)q);
                    mn = min(mn, (int)(q >> 32));
                }
                if (__all(mn >= thr)) break;
                if (++guard > (1 << 14)) break;
            }
        }
        __syncthreads();

        const bool act = isL1 ? (t < SEQT) : (t >= 1 && t <= SEQT);
        if (act) {
            v16f v1, v2;
#pragma unroll
            for (int k = 0; k < 16; ++k) {
                v1[k] = h1s[lane + 64 * k];
                v2[k] = h2s[lane + 64 * k] * zmask;
            }
            float a0 = 0.f, a1 = 0.f, a2 = 0.f, a3 = 0.f;
#pragma unroll
            for (int k = 0; k < 16; ++k) {
                a0 = fmaf(A0[k], v1[k], a0);
                a1 = fmaf(A1[k], v1[k], a1);
                a2 = fmaf(A2[k], v1[k], a2);
                a3 = fmaf(A3[k], v1[k], a3);
            }
#pragma unroll
            for (int k = 0; k < 16; ++k) {
                a0 = fmaf(B0[k], v2[k], a0);
                a1 = fmaf(B1[k], v2[k], a1);
                a2 = fmaf(B2[k], v2[k], a2);
                a3 = fmaf(B3[k], v2[k], a3);
            }
#pragma unroll
            for (int s = 32; s; s >>= 1) {
                a0 += __shfl_xor(a0, s);
                a1 += __shfl_xor(a1, s);
                a2 += __shfl_xor(a2, s);
                a3 += __shfl_xor(a3, s);
            }
            const float xg = xsel * ((t < SEQT) ? seqs[t] : 0.f);
            float i_ = sig_(a0 + xg * wx0 + bb0);
            float f_ = sig_(a1 + xg * wx1 + bb1);
            float g_ = tanhf(a2 + xg * wx2 + bb2);
            float o_ = sig_(a3 + xg * wx3 + bb3);
            c = f_ * c + i_ * g_;
            float h = o_ * tanhf(c);
            if (lane == 0) {
                const int ps = isL1 ? t : (t - 1);   // produced timestep
                stp(pub + (ps & 1) * HID + r,
                    ((u64)(unsigned)(ps + 1) << 32) | (u64)__float_as_uint(h));
            }
        }

        // out(t-2) from staged h2s (carrier also did its row-gate work above)
        if (carrier && t >= 2) {
            float ov = 0.f;
#pragma unroll
            for (int k = 0; k < 16; ++k) ov = fmaf(WL[k], h2s[lane + 64 * k], ov);
#pragma unroll
            for (int s = 32; s; s >>= 1) ov += __shfl_xor(ov, s);
            if (lane == 0) out[t - 2] = ov + blin;
        }

        __syncthreads();   // protect LDS from next step's restaging
    }
}

extern "C" void kernel_launch(void* const* d_in, const int* in_sizes, int n_in,
                              void* d_out, int out_size, void* d_ws, size_t ws_size,
                              hipStream_t stream)
{
    (void)hipMemsetAsync(d_ws, 0, WS_BYTES, stream);

    const float* seq  = (const float*)d_in[0];
    const float* wih1 = (const float*)d_in[1];
    const float* whh1 = (const float*)d_in[2];
    const float* bih1 = (const float*)d_in[3];
    const float* bhh1 = (const float*)d_in[4];
    const float* wih2 = (const float*)d_in[5];
    const float* whh2 = (const float*)d_in[6];
    const float* bih2 = (const float*)d_in[7];
    const float* bhh2 = (const float*)d_in[8];
    const float* wlin = (const float*)d_in[9];
    const float* blin = (const float*)d_in[10];
    float* out = (float*)d_out;
    u64*   ws  = (u64*)d_ws;

    hipLaunchKernelGGL(lstm_hyb, dim3(NBLK), dim3(TPB), 0, stream,
                       seq, wih1, whh1, bih1, bhh1,
                       wih2, whh2, bih2, bhh2, wlin, blin,
                       out, ws);
}